// Round 5
// baseline (83.917 us; speedup 1.0000x reference)
//
#include <hip/hip_runtime.h>
#include <math.h>

#define NMAX   64
#define NSITES 12
#define BLOCK  1024   // 16 waves share ONE table copy -> big table at full occ
#define EPB    256    // elements per block: wave w -> q=w&3 (site group), eb=(w>>2)*64+lane
#define RS     68     // neighbor row stride (floats), 16B-aligned rows

#define B_SOFT 0.01f
#define PAD_C  14.0f  // sentinel coord: r2 in [~128,~800] -> f ~ 1e-6, inside table
#define R2_BASE_BITS 0x2B800000u   // bits of 2^-40 (table low edge)
#define TBL_N  6400   // piecewise-CONSTANT f32, 128 bins/octave, r2 in [2^-40, 2^10)
                      // (real r2 <= ~250, sentinel <= ~800 -> no clamps anywhere)

#define NB_F   (NSITES * RS)          // 816
#define GW_NBX TBL_N
#define GW_NBY (GW_NBX + NB_F)
#define GW_F   (GW_NBY + NB_F)        // 8032 floats

// LDS float layout: table [0,6400) | nbx | nby | partials
#define L_NBX  TBL_N
#define L_NBY  (L_NBX + NB_F)
#define L_PART (L_NBY + NB_F)
#define SMEM_F (L_PART + 3 * EPB)     // 8800 floats = 35200 B -> 2 blocks/CU = 32 waves

__device__ __align__(16) float g_ws[GW_F];
__device__ int g_mq[4];

typedef float v2f __attribute__((ext_vector_type(2)));
typedef float v4f __attribute__((ext_vector_type(4)));

// f(r2) = exp(-sqrt(r2)) / (sqrt(r2) + b), exact (init kernel only)
__device__ __forceinline__ float f_exact(float r2) {
    const float r = sqrtf(r2);
    return expf(-r) / (r + B_SOFT);
}

#define INIT_BLOCKS 26   // 26*256 = 6656 >= TBL_N

// Build table (all blocks, disjoint slices) + compact neighbors (block 0).
__global__ void init_kernel(const float* __restrict__ neighbors,
                            const float* __restrict__ mask) {
    const int tid = threadIdx.x;
    const int gid = blockIdx.x * 256 + tid;

    if (gid < TBL_N) {
        // bin i covers r2-bits [BASE + (i<<16), BASE + ((i+1)<<16));
        // c = (f(lo)+f(hi))/2 is L-inf optimal for monotone f.
        const unsigned b0 = R2_BASE_BITS + ((unsigned)gid << 16);
        const unsigned b1 = b0 + (1u << 16);
        const float f0 = f_exact(__builtin_bit_cast(float, b0));
        const float f1 = f_exact(__builtin_bit_cast(float, b1));
        g_ws[gid] = 0.5f * (f0 + f1);
    }

    if (blockIdx.x == 0) {
        __shared__ int cnt[NSITES];
        const int wv = tid >> 6, lane = tid & 63;
        // Sentinel fill: slots past a site's count -> r2 in [128,800] -> f~1e-6.
        for (int i = tid; i < 2 * NB_F; i += 256) g_ws[GW_NBX + i] = PAD_C;
        __syncthreads();

        for (int s = wv; s < NSITES; s += 4) {
            const bool keep = mask[s * NMAX + lane] > 0.5f;
            const unsigned long long bal = __ballot(keep);
            if (keep) {
                const int pos = __popcll(bal & ((1ull << lane) - 1ull));
                const float2 p = ((const float2*)neighbors)[s * NMAX + lane];
                g_ws[GW_NBX + s * RS + pos] = p.x;
                g_ws[GW_NBY + s * RS + pos] = p.y;
            }
            if (lane == 0) cnt[s] = __popcll(bal);
        }
        __syncthreads();
        if (tid < 4) {   // per-q loop bound: max over that group's 3 sites
            const int mm = max(cnt[3 * tid],
                           max(cnt[3 * tid + 1], cnt[3 * tid + 2]));
            g_mq[tid] = (mm + 3) & ~3;   // <= 64, RS-safe
        }
    }
}

__global__ __launch_bounds__(BLOCK, 2)
void pot_energy_kernel(const float* __restrict__ x,
                       float* __restrict__ out, int B) {
    __shared__ __align__(16) float smem[SMEM_F];
    const int tid  = threadIdx.x;
    const int w    = tid >> 6;
    const int lane = tid & 63;

    // Prologue: copy table + compacted neighbors from L2-hot device global.
    {
        const float4* s4 = (const float4*)g_ws;
        float4* d4 = (float4*)smem;
        #pragma unroll
        for (int i0 = 0; i0 < 2; ++i0) {
            const int i = tid + i0 * BLOCK;
            if (i < GW_F / 4) d4[i] = s4[i];
        }
    }
    const int q = __builtin_amdgcn_readfirstlane(w & 3);  // site group (uniform)
    const int m = g_mq[q];                                // scalar load
    __syncthreads();

    const int eb = ((w >> 2) << 6) + lane;   // element within block: 0..255
    const int e  = blockIdx.x * EPB + eb;
    const int el = (e < B) ? e : 0;

    // This wave's 3 site positions for element e: 6 contiguous floats.
    const float* xb = x + (size_t)el * 24 + q * 6;
    const float2 pa = ((const float2*)xb)[0];
    const float2 pb = ((const float2*)xb)[1];
    const float2 pc = ((const float2*)xb)[2];
    const float xs_[3] = { pa.x, pb.x, pc.x };
    const float ys_[3] = { pa.y, pb.y, pc.y };

    const char* tbl = (const char*)smem;                 // table at LDS byte 0
    const v2f eps2 = { 9.094947e-13f, 9.094947e-13f };   // 2^-40 floor, in-fma

    float acc0 = 0.f, acc1 = 0.f;   // 2 add chains for ILP
    #pragma unroll
    for (int s = 0; s < 3; ++s) {
        const int site = q * 3 + s;
        // All 64 lanes read the SAME address -> pure broadcast, conflict-free.
        const float* __restrict__ rx = smem + L_NBX + site * RS;
        const float* __restrict__ ry = smem + L_NBY + site * RS;
        const v2f xs2 = { xs_[s], xs_[s] };
        const v2f ys2 = { ys_[s], ys_[s] };
        #pragma unroll 2
        for (int j0 = 0; j0 < m; j0 += 4) {
            const v4f nx4 = *(const v4f*)(rx + j0);
            const v4f ny4 = *(const v4f*)(ry + j0);
            const v2f dxA = xs2 - nx4.xy;
            const v2f dxB = xs2 - nx4.zw;
            const v2f dyA = ys2 - ny4.xy;
            const v2f dyB = ys2 - ny4.zw;
            // eps folded into the fma chain: r2 >= 2^-40, no low clamp op
            const v2f r2A = __builtin_elementwise_fma(
                dyA, dyA, __builtin_elementwise_fma(dxA, dxA, eps2));
            const v2f r2B = __builtin_elementwise_fma(
                dyB, dyB, __builtin_elementwise_fma(dxB, dxB, eps2));
            const float r2k[4] = { r2A.x, r2A.y, r2B.x, r2B.y };
            #pragma unroll
            for (int k = 0; k < 4; ++k) {
                // b32 gather: 64 bank-touches/wave (was 128 with b64 lerp)
                const unsigned bits = __builtin_bit_cast(unsigned, r2k[k]);
                const unsigned off  = ((bits >> 14) & ~3u)
                                      - (R2_BASE_BITS >> 14);
                const float c = *(const float*)(tbl + off);
                if (k & 1) acc1 += c; else acc0 += c;
            }
        }
    }

    // Combine the 4 q-partials of each element via LDS (conflict-free strides).
    const float av = acc0 + acc1;
    if (q != 0) smem[L_PART + (q - 1) * EPB + eb] = av;
    __syncthreads();
    if (q == 0 && e < B) {
        out[e] = av + smem[L_PART + eb]
                    + smem[L_PART + EPB + eb]
                    + smem[L_PART + 2 * EPB + eb];   // coalesced store
    }
}

extern "C" void kernel_launch(void* const* d_in, const int* in_sizes, int n_in,
                              void* d_out, int out_size, void* d_ws, size_t ws_size,
                              hipStream_t stream) {
    const float* x   = (const float*)d_in[0];
    const float* nbr = (const float*)d_in[1];
    const float* msk = (const float*)d_in[2];
    float* out = (float*)d_out;

    const int B = in_sizes[0] / 24;

    init_kernel<<<INIT_BLOCKS, 256, 0, stream>>>(nbr, msk);

    const int blocks = (B + EPB - 1) / EPB;
    pot_energy_kernel<<<blocks, BLOCK, 0, stream>>>(x, out, B);
}